// Round 1
// baseline (473.056 us; speedup 1.0000x reference)
//
#include <hip/hip_runtime.h>

typedef __attribute__((ext_vector_type(8))) __bf16 bf16x8;
typedef __attribute__((ext_vector_type(4))) float f32x4;
typedef __attribute__((ext_vector_type(8))) unsigned short u16x8;

__device__ __forceinline__ unsigned short f2bf(float f) {
  unsigned int u = __builtin_bit_cast(unsigned int, f);
  u += 0x7FFFu + ((u >> 16) & 1u);
  return (unsigned short)(u >> 16);
}

#define KDIM 1024

// ---------- weight packing: out[n][k] = in[h][k][o]*scale, n = h*64+o ----------
__global__ __launch_bounds__(256) void pack_wqkv(const float* __restrict__ w,
                                                 unsigned short* __restrict__ out,
                                                 float scale) {
  int i = blockIdx.x * 256 + threadIdx.x;   // over 1024*1024, out-coalesced
  int n = i >> 10, k = i & 1023;
  int h = n >> 6, o = n & 63;
  out[i] = f2bf(w[h * 65536 + k * 64 + o] * scale);
}

// projection kernel (H,HS,D_OUT): out[o][ki] = in[ki/64][ki%64][o] = in_flat[ki*1024+o]
__global__ __launch_bounds__(256) void pack_wp(const float* __restrict__ w,
                                               unsigned short* __restrict__ out) {
  int i = blockIdx.x * 256 + threadIdx.x;
  int o = i >> 10, ki = i & 1023;
  out[i] = f2bf(w[ki * 1024 + o]);
}

// ---------- GEMM: C[M][1024] = A[M][1024] x B, B given pre-transposed Wt[n][k] ----------
#define LSTR 72   // LDS row stride in bf16 elems (64 + 8 pad -> 144B rows, 2-way free)

template <bool AF32, bool OUTF32>
__global__ __launch_bounds__(256) void gemm_k(const void* __restrict__ Ap,
                                              const unsigned short* __restrict__ Wt,
                                              void* __restrict__ Cp,
                                              const float* __restrict__ bias) {
  __shared__ unsigned short As[128 * LSTR];
  __shared__ unsigned short Bs[128 * LSTR];
  const int t = threadIdx.x;
  const int lane = t & 63, w = t >> 6;
  const int wr = (w >> 1) * 64, wc = (w & 1) * 64;
  const int l15 = lane & 15, lh = lane >> 4;
  const int rL = t >> 1;             // staging row 0..127
  const int c0 = (t & 1) * 32;       // staging k-offset
  const long rowA = (long)blockIdx.y * 128 + rL;
  const long rowB = (long)blockIdx.x * 128 + rL;

  f32x4 acc[4][4];
#pragma unroll
  for (int i = 0; i < 4; ++i)
#pragma unroll
    for (int j = 0; j < 4; ++j) acc[i][j] = {0.f, 0.f, 0.f, 0.f};

  for (int k0 = 0; k0 < KDIM; k0 += 64) {
    if (k0) __syncthreads();
    if constexpr (AF32) {
      const float* src = (const float*)Ap + rowA * KDIM + k0 + c0;
      unsigned short* dst = &As[rL * LSTR + c0];
#pragma unroll
      for (int e = 0; e < 32; e += 8) {
        float4 v0 = *reinterpret_cast<const float4*>(src + e);
        float4 v1 = *reinterpret_cast<const float4*>(src + e + 4);
        u16x8 o;
        o[0] = f2bf(v0.x); o[1] = f2bf(v0.y); o[2] = f2bf(v0.z); o[3] = f2bf(v0.w);
        o[4] = f2bf(v1.x); o[5] = f2bf(v1.y); o[6] = f2bf(v1.z); o[7] = f2bf(v1.w);
        *reinterpret_cast<u16x8*>(dst + e) = o;
      }
    } else {
      const unsigned short* src = (const unsigned short*)Ap + rowA * KDIM + k0 + c0;
      unsigned short* dst = &As[rL * LSTR + c0];
#pragma unroll
      for (int e = 0; e < 32; e += 8)
        *reinterpret_cast<u16x8*>(dst + e) = *reinterpret_cast<const u16x8*>(src + e);
    }
    {
      const unsigned short* src = Wt + rowB * KDIM + k0 + c0;
      unsigned short* dst = &Bs[rL * LSTR + c0];
#pragma unroll
      for (int e = 0; e < 32; e += 8)
        *reinterpret_cast<u16x8*>(dst + e) = *reinterpret_cast<const u16x8*>(src + e);
    }
    __syncthreads();
#pragma unroll
    for (int kc = 0; kc < 2; ++kc) {
      bf16x8 af[4], bfr[4];
#pragma unroll
      for (int mi = 0; mi < 4; ++mi)
        af[mi] = *reinterpret_cast<const bf16x8*>(&As[(wr + mi * 16 + l15) * LSTR + kc * 32 + lh * 8]);
#pragma unroll
      for (int ni = 0; ni < 4; ++ni)
        bfr[ni] = *reinterpret_cast<const bf16x8*>(&Bs[(wc + ni * 16 + l15) * LSTR + kc * 32 + lh * 8]);
#pragma unroll
      for (int mi = 0; mi < 4; ++mi)
#pragma unroll
        for (int ni = 0; ni < 4; ++ni)
          acc[mi][ni] = __builtin_amdgcn_mfma_f32_16x16x32_bf16(af[mi], bfr[ni], acc[mi][ni], 0, 0, 0);
    }
  }
  const long rbase = (long)blockIdx.y * 128 + wr;
  const long cbase = (long)blockIdx.x * 128 + wc;
#pragma unroll
  for (int ni = 0; ni < 4; ++ni) {
    const long col = cbase + ni * 16 + l15;
    float bv = 0.f;
    if constexpr (OUTF32) bv = bias[col];
#pragma unroll
    for (int mi = 0; mi < 4; ++mi) {
      const long row = rbase + mi * 16 + lh * 4;
#pragma unroll
      for (int j = 0; j < 4; ++j) {
        if constexpr (OUTF32)
          ((float*)Cp)[(row + j) * KDIM + col] = acc[mi][ni][j] + bv;
        else
          ((unsigned short*)Cp)[(row + j) * KDIM + col] = f2bf(acc[mi][ni][j]);
      }
    }
  }
}

// ---------- flash attention: grid (N/64, B*H), 4 waves x 16 q-rows ----------
__global__ __launch_bounds__(256) void attn_k(const unsigned short* __restrict__ Qp,
                                              const unsigned short* __restrict__ Kp,
                                              const unsigned short* __restrict__ Vp,
                                              unsigned short* __restrict__ Op) {
  constexpr int LST = 72;
  __shared__ unsigned short Ql[64 * LST];
  __shared__ unsigned short Kl[64 * LST];
  __shared__ unsigned short Vt[64 * LST];   // transposed V: Vt[hs][m]
  __shared__ unsigned short Pl[64 * LST];
  const int t = threadIdx.x;
  const int lane = t & 63, w = t >> 6;
  const int l15 = lane & 15, lh = lane >> 4;
  const int bh = blockIdx.y;
  const long base = (long)(bh >> 4) * 2048 * 1024 + (long)(bh & 15) * 64;
  const int n0 = blockIdx.x * 64;
  const int sr = t >> 2, sc = (t & 3) * 16;

  {
    const unsigned short* src = Qp + base + (long)(n0 + sr) * 1024 + sc;
    *reinterpret_cast<u16x8*>(&Ql[sr * LST + sc]) = *reinterpret_cast<const u16x8*>(src);
    *reinterpret_cast<u16x8*>(&Ql[sr * LST + sc + 8]) = *reinterpret_cast<const u16x8*>(src + 8);
  }
  __syncthreads();
  bf16x8 qf[2];
#pragma unroll
  for (int kc = 0; kc < 2; ++kc)
    qf[kc] = *reinterpret_cast<const bf16x8*>(&Ql[(w * 16 + l15) * LST + kc * 32 + lh * 8]);

  float mrun[4], lrun[4];
  f32x4 accO[4];
#pragma unroll
  for (int j = 0; j < 4; ++j) { mrun[j] = -1e30f; lrun[j] = 0.f; }
#pragma unroll
  for (int vf = 0; vf < 4; ++vf) accO[vf] = {0.f, 0.f, 0.f, 0.f};

  for (int m0 = 0; m0 < 2048; m0 += 64) {
    __syncthreads();
    {
      const unsigned short* srcK = Kp + base + (long)(m0 + sr) * 1024 + sc;
      *reinterpret_cast<u16x8*>(&Kl[sr * LST + sc]) = *reinterpret_cast<const u16x8*>(srcK);
      *reinterpret_cast<u16x8*>(&Kl[sr * LST + sc + 8]) = *reinterpret_cast<const u16x8*>(srcK + 8);
      const unsigned short* srcV = Vp + base + (long)(m0 + sr) * 1024 + sc;
      u16x8 v0 = *reinterpret_cast<const u16x8*>(srcV);
      u16x8 v1 = *reinterpret_cast<const u16x8*>(srcV + 8);
#pragma unroll
      for (int e = 0; e < 8; ++e) {
        Vt[(sc + e) * LST + sr] = v0[e];
        Vt[(sc + 8 + e) * LST + sr] = v1[e];
      }
    }
    __syncthreads();

    f32x4 s[4];
#pragma unroll
    for (int nf = 0; nf < 4; ++nf) {
      s[nf] = {0.f, 0.f, 0.f, 0.f};
#pragma unroll
      for (int kc = 0; kc < 2; ++kc) {
        bf16x8 kf = *reinterpret_cast<const bf16x8*>(&Kl[(nf * 16 + l15) * LST + kc * 32 + lh * 8]);
        s[nf] = __builtin_amdgcn_mfma_f32_16x16x32_bf16(qf[kc], kf, s[nf], 0, 0, 0);
      }
    }

    float mnew[4], scl[4];
#pragma unroll
    for (int j = 0; j < 4; ++j) {
      float mx = fmaxf(fmaxf(s[0][j], s[1][j]), fmaxf(s[2][j], s[3][j]));
#pragma unroll
      for (int d = 1; d < 16; d <<= 1) mx = fmaxf(mx, __shfl_xor(mx, d));
      mnew[j] = fmaxf(mrun[j], mx);
      scl[j] = __expf(mrun[j] - mnew[j]);
      mrun[j] = mnew[j];
    }
    float p[4][4];
#pragma unroll
    for (int nf = 0; nf < 4; ++nf)
#pragma unroll
      for (int j = 0; j < 4; ++j)
        p[nf][j] = __expf(s[nf][j] - mnew[j]);
#pragma unroll
    for (int j = 0; j < 4; ++j) {
      float sm = p[0][j] + p[1][j] + p[2][j] + p[3][j];
#pragma unroll
      for (int d = 1; d < 16; d <<= 1) sm += __shfl_xor(sm, d);
      lrun[j] = lrun[j] * scl[j] + sm;
    }
#pragma unroll
    for (int vf = 0; vf < 4; ++vf)
#pragma unroll
      for (int j = 0; j < 4; ++j) accO[vf][j] *= scl[j];

#pragma unroll
    for (int nf = 0; nf < 4; ++nf)
#pragma unroll
      for (int j = 0; j < 4; ++j)
        Pl[(w * 16 + lh * 4 + j) * LST + nf * 16 + l15] = f2bf(p[nf][j]);

#pragma unroll
    for (int kc = 0; kc < 2; ++kc) {
      bf16x8 pf = *reinterpret_cast<const bf16x8*>(&Pl[(w * 16 + l15) * LST + kc * 32 + lh * 8]);
#pragma unroll
      for (int vf = 0; vf < 4; ++vf) {
        bf16x8 vfr = *reinterpret_cast<const bf16x8*>(&Vt[(vf * 16 + l15) * LST + kc * 32 + lh * 8]);
        accO[vf] = __builtin_amdgcn_mfma_f32_16x16x32_bf16(pf, vfr, accO[vf], 0, 0, 0);
      }
    }
  }

#pragma unroll
  for (int j = 0; j < 4; ++j) {
    float inv = 1.f / lrun[j];
    const long row = n0 + w * 16 + lh * 4 + j;
#pragma unroll
    for (int vf = 0; vf < 4; ++vf)
      Op[base + row * 1024 + vf * 16 + l15] = f2bf(accO[vf][j] * inv);
  }
}

extern "C" void kernel_launch(void* const* d_in, const int* in_sizes, int n_in,
                              void* d_out, int out_size, void* d_ws, size_t ws_size,
                              hipStream_t stream) {
  const float* q    = (const float*)d_in[0];
  const float* k    = (const float*)d_in[1];
  const float* v    = (const float*)d_in[2];
  const float* wq   = (const float*)d_in[3];
  const float* wk   = (const float*)d_in[4];
  const float* wv   = (const float*)d_in[5];
  const float* wp   = (const float*)d_in[6];
  const float* bias = (const float*)d_in[7];

  unsigned short* ws = (unsigned short*)d_ws;
  unsigned short* Wq = ws;
  unsigned short* Wk = Wq + (1 << 20);
  unsigned short* Wv = Wk + (1 << 20);
  unsigned short* Wp = Wv + (1 << 20);
  unsigned short* qp = Wp + (1 << 20);
  unsigned short* kp = qp + (8 << 20);
  unsigned short* vp = kp + (8 << 20);
  unsigned short* mh = vp + (8 << 20);

  pack_wqkv<<<4096, 256, 0, stream>>>(wq, Wq, 0.125f);  // fold 1/sqrt(64)
  pack_wqkv<<<4096, 256, 0, stream>>>(wk, Wk, 1.0f);
  pack_wqkv<<<4096, 256, 0, stream>>>(wv, Wv, 1.0f);
  pack_wp  <<<4096, 256, 0, stream>>>(wp, Wp);

  dim3 gg(8, 64);  // (1024/128 col tiles, 8192/128 row tiles)
  gemm_k<true, false><<<gg, 256, 0, stream>>>(q, Wq, qp, nullptr);
  gemm_k<true, false><<<gg, 256, 0, stream>>>(k, Wk, kp, nullptr);
  gemm_k<true, false><<<gg, 256, 0, stream>>>(v, Wv, vp, nullptr);

  attn_k<<<dim3(32, 64), 256, 0, stream>>>(qp, kp, vp, mh);

  gemm_k<false, true><<<gg, 256, 0, stream>>>(mh, Wp, d_out, bias);
}

// Round 2
// 369.595 us; speedup vs baseline: 1.2799x; 1.2799x over previous
//
#include <hip/hip_runtime.h>

typedef __attribute__((ext_vector_type(8))) __bf16 bf16x8;
typedef __attribute__((ext_vector_type(4))) float f32x4;
typedef __attribute__((ext_vector_type(8))) unsigned short u16x8;

__device__ __forceinline__ unsigned short f2bf(float f) {
  unsigned int u = __builtin_bit_cast(unsigned int, f);
  u += 0x7FFFu + ((u >> 16) & 1u);
  return (unsigned short)(u >> 16);
}
__device__ __forceinline__ unsigned int pk2(float a, float b) {
  return (unsigned int)f2bf(a) | ((unsigned int)f2bf(b) << 16);
}

#define KDIM 1024

// ---------- weight packing: out[n][k] = in[h][k][o]*scale, n = h*64+o ----------
__global__ __launch_bounds__(256) void pack_wqkv(const float* __restrict__ w,
                                                 unsigned short* __restrict__ out,
                                                 float scale) {
  int i = blockIdx.x * 256 + threadIdx.x;
  int n = i >> 10, k = i & 1023;
  int h = n >> 6, o = n & 63;
  out[i] = f2bf(w[h * 65536 + k * 64 + o] * scale);
}

__global__ __launch_bounds__(256) void pack_wp(const float* __restrict__ w,
                                               unsigned short* __restrict__ out) {
  int i = blockIdx.x * 256 + threadIdx.x;
  int o = i >> 10, ki = i & 1023;
  out[i] = f2bf(w[ki * 1024 + o]);
}

// ---------- GEMM: C[M][1024] = A[M][1024] x B, B pre-transposed Wt[n][k] ----------
#define LSTR 72

template <bool AF32, bool OUTF32, bool OUTT>
__global__ __launch_bounds__(256) void gemm_k(const void* __restrict__ Ap,
                                              const unsigned short* __restrict__ Wt,
                                              void* __restrict__ Cp,
                                              const float* __restrict__ bias) {
  __shared__ unsigned short As[128 * LSTR];
  __shared__ unsigned short Bs[128 * LSTR];
  const int t = threadIdx.x;
  const int lane = t & 63, w = t >> 6;
  const int wr = (w >> 1) * 64, wc = (w & 1) * 64;
  const int l15 = lane & 15, lh = lane >> 4;
  const int rL = t >> 1;
  const int c0 = (t & 1) * 32;
  const long rowA = (long)blockIdx.y * 128 + rL;
  const long rowB = (long)blockIdx.x * 128 + rL;

  f32x4 acc[4][4];
#pragma unroll
  for (int i = 0; i < 4; ++i)
#pragma unroll
    for (int j = 0; j < 4; ++j) acc[i][j] = {0.f, 0.f, 0.f, 0.f};

  for (int k0 = 0; k0 < KDIM; k0 += 64) {
    if (k0) __syncthreads();
    if constexpr (AF32) {
      const float* src = (const float*)Ap + rowA * KDIM + k0 + c0;
      unsigned short* dst = &As[rL * LSTR + c0];
#pragma unroll
      for (int e = 0; e < 32; e += 8) {
        float4 v0 = *reinterpret_cast<const float4*>(src + e);
        float4 v1 = *reinterpret_cast<const float4*>(src + e + 4);
        u16x8 o;
        o[0] = f2bf(v0.x); o[1] = f2bf(v0.y); o[2] = f2bf(v0.z); o[3] = f2bf(v0.w);
        o[4] = f2bf(v1.x); o[5] = f2bf(v1.y); o[6] = f2bf(v1.z); o[7] = f2bf(v1.w);
        *reinterpret_cast<u16x8*>(dst + e) = o;
      }
    } else {
      const unsigned short* src = (const unsigned short*)Ap + rowA * KDIM + k0 + c0;
      unsigned short* dst = &As[rL * LSTR + c0];
#pragma unroll
      for (int e = 0; e < 32; e += 8)
        *reinterpret_cast<u16x8*>(dst + e) = *reinterpret_cast<const u16x8*>(src + e);
    }
    {
      const unsigned short* src = Wt + rowB * KDIM + k0 + c0;
      unsigned short* dst = &Bs[rL * LSTR + c0];
#pragma unroll
      for (int e = 0; e < 32; e += 8)
        *reinterpret_cast<u16x8*>(dst + e) = *reinterpret_cast<const u16x8*>(src + e);
    }
    __syncthreads();
#pragma unroll
    for (int kc = 0; kc < 2; ++kc) {
      bf16x8 af[4], bfr[4];
#pragma unroll
      for (int mi = 0; mi < 4; ++mi)
        af[mi] = *reinterpret_cast<const bf16x8*>(&As[(wr + mi * 16 + l15) * LSTR + kc * 32 + lh * 8]);
#pragma unroll
      for (int ni = 0; ni < 4; ++ni)
        bfr[ni] = *reinterpret_cast<const bf16x8*>(&Bs[(wc + ni * 16 + l15) * LSTR + kc * 32 + lh * 8]);
#pragma unroll
      for (int mi = 0; mi < 4; ++mi)
#pragma unroll
        for (int ni = 0; ni < 4; ++ni)
          acc[mi][ni] = __builtin_amdgcn_mfma_f32_16x16x32_bf16(af[mi], bfr[ni], acc[mi][ni], 0, 0, 0);
    }
  }
  const long rbase = (long)blockIdx.y * 128 + wr;
  const long cbase = (long)blockIdx.x * 128 + wc;
#pragma unroll
  for (int ni = 0; ni < 4; ++ni) {
    const long col = cbase + ni * 16 + l15;
    float bv = 0.f;
    if constexpr (OUTF32) bv = bias[col];
#pragma unroll
    for (int mi = 0; mi < 4; ++mi) {
      const long row = rbase + mi * 16 + lh * 4;
#pragma unroll
      for (int j = 0; j < 4; ++j) {
        if constexpr (OUTT) {
          // Vt_g[b][col][m]: b = row>>11, m = row&2047
          const long r = row + j;
          ((unsigned short*)Cp)[(r >> 11) * 2097152 + col * 2048 + (r & 2047)] = f2bf(acc[mi][ni][j]);
        } else if constexpr (OUTF32) {
          ((float*)Cp)[(row + j) * KDIM + col] = acc[mi][ni][j] + bv;
        } else {
          ((unsigned short*)Cp)[(row + j) * KDIM + col] = f2bf(acc[mi][ni][j]);
        }
      }
    }
  }
}

// ---------- flash attention, swapped-QK variant ----------
// grid (N/64, B*H), 4 waves x 16 q-rows. K in LDS (padded), V^T in LDS (padded,
// from globally pre-transposed Vt_g). Softmax in-register (q = lane&15),
// P->A-frag via 16 bpermute + select. No P LDS roundtrip.
__global__ __launch_bounds__(256) void attn_k(const unsigned short* __restrict__ Qp,
                                              const unsigned short* __restrict__ Kp,
                                              const unsigned short* __restrict__ Vtg,
                                              unsigned short* __restrict__ Op) {
  constexpr int LST = 72;
  __shared__ unsigned short Kl[64 * LST];
  __shared__ unsigned short Vl[64 * LST];   // Vl[hs][m]
  const int t = threadIdx.x;
  const int lane = t & 63, w = t >> 6;
  const int l15 = lane & 15, lh = lane >> 4;
  const int bh = blockIdx.y;
  const long base = (long)(bh >> 4) * 2097152 + (long)(bh & 15) * 64;  // [b][n][h*64]
  const long vbase = (long)bh * 131072;                                // [bh][hs][m]
  const int n0 = blockIdx.x * 64;
  const int sr = t >> 2, sc = (t & 3) * 16;

  // Q fragments straight from global: Q[q = w*16+l15][k = kc*32 + lh*8 ..+8]
  bf16x8 qf[2];
  {
    const unsigned short* qsrc = Qp + base + (long)(n0 + w * 16 + l15) * 1024 + lh * 8;
    qf[0] = *reinterpret_cast<const bf16x8*>(qsrc);
    qf[1] = *reinterpret_cast<const bf16x8*>(qsrc + 32);
  }

  const unsigned short* ksrc = Kp + base + (long)sr * 1024 + sc;
  const unsigned short* vsrc = Vtg + vbase + (long)sr * 2048 + sc;
  u16x8 kr0 = *reinterpret_cast<const u16x8*>(ksrc);
  u16x8 kr1 = *reinterpret_cast<const u16x8*>(ksrc + 8);
  u16x8 vr0 = *reinterpret_cast<const u16x8*>(vsrc);
  u16x8 vr1 = *reinterpret_cast<const u16x8*>(vsrc + 8);

  float mrun = -3e38f, lrun = 0.f;
  f32x4 accO[4];
#pragma unroll
  for (int vf = 0; vf < 4; ++vf) accO[vf] = {0.f, 0.f, 0.f, 0.f};

  for (int m0 = 0; m0 < 2048; m0 += 64) {
    *reinterpret_cast<u16x8*>(&Kl[sr * LST + sc]) = kr0;
    *reinterpret_cast<u16x8*>(&Kl[sr * LST + sc + 8]) = kr1;
    *reinterpret_cast<u16x8*>(&Vl[sr * LST + sc]) = vr0;
    *reinterpret_cast<u16x8*>(&Vl[sr * LST + sc + 8]) = vr1;
    __syncthreads();
    if (m0 + 64 < 2048) {  // async prefetch next tile into regs (lands during compute)
      kr0 = *reinterpret_cast<const u16x8*>(ksrc + (long)(m0 + 64) * 1024);
      kr1 = *reinterpret_cast<const u16x8*>(ksrc + (long)(m0 + 64) * 1024 + 8);
      vr0 = *reinterpret_cast<const u16x8*>(vsrc + m0 + 64);
      vr1 = *reinterpret_cast<const u16x8*>(vsrc + m0 + 72);
    }

    // S^T[m][q] = mfma(K_frag, Q_frag): lane holds sp[nf][r] = S[m=nf*16+lh*4+r][q=l15]
    f32x4 sp[4];
#pragma unroll
    for (int nf = 0; nf < 4; ++nf) {
      f32x4 z = {0.f, 0.f, 0.f, 0.f};
      bf16x8 kf0 = *reinterpret_cast<const bf16x8*>(&Kl[(nf * 16 + l15) * LST + lh * 8]);
      bf16x8 kf1 = *reinterpret_cast<const bf16x8*>(&Kl[(nf * 16 + l15) * LST + 32 + lh * 8]);
      z = __builtin_amdgcn_mfma_f32_16x16x32_bf16(kf0, qf[0], z, 0, 0, 0);
      sp[nf] = __builtin_amdgcn_mfma_f32_16x16x32_bf16(kf1, qf[1], z, 0, 0, 0);
    }

    // online softmax over m (local 16 + butterfly across lanes sharing q)
    float mx = -3e38f;
#pragma unroll
    for (int nf = 0; nf < 4; ++nf)
#pragma unroll
      for (int r = 0; r < 4; ++r) mx = fmaxf(mx, sp[nf][r]);
    mx = fmaxf(mx, __shfl_xor(mx, 16));
    mx = fmaxf(mx, __shfl_xor(mx, 32));
    float mnew = fmaxf(mrun, mx);
    float scl = __expf(mrun - mnew);
    mrun = mnew;

    float p[4][4];
    float ls = 0.f;
#pragma unroll
    for (int nf = 0; nf < 4; ++nf)
#pragma unroll
      for (int r = 0; r < 4; ++r) {
        p[nf][r] = __expf(sp[nf][r] - mnew);
        ls += p[nf][r];
      }
    ls += __shfl_xor(ls, 16);
    ls += __shfl_xor(ls, 32);
    lrun = lrun * scl + ls;

    // rescale accO (accO q-index = lh*4+r; scl lives at lane q)
#pragma unroll
    for (int r = 0; r < 4; ++r) {
      float sclr = __shfl(scl, lh * 4 + r);
#pragma unroll
      for (int vf = 0; vf < 4; ++vf) accO[vf][r] *= sclr;
    }

    // pack P and exchange into A-fragment layout: lane needs P[q=l15][m=kc*32+lh*8+e]
    unsigned int W[4][2];
#pragma unroll
    for (int nf = 0; nf < 4; ++nf) {
      W[nf][0] = pk2(p[nf][0], p[nf][1]);
      W[nf][1] = pk2(p[nf][2], p[nf][3]);
    }
    const int sA = (lh & 1) * 32 + l15;
    const int sB = sA + 16;
    const bool hi = lh >= 2;   // selects nf = kc*2 + (lh>>1)
    bf16x8 pa[2];
#pragma unroll
    for (int kc = 0; kc < 2; ++kc) {
      unsigned int a0 = (unsigned int)__shfl((int)W[kc * 2][0], sA);
      unsigned int a1 = (unsigned int)__shfl((int)W[kc * 2][1], sA);
      unsigned int a2 = (unsigned int)__shfl((int)W[kc * 2][0], sB);
      unsigned int a3 = (unsigned int)__shfl((int)W[kc * 2][1], sB);
      unsigned int b0 = (unsigned int)__shfl((int)W[kc * 2 + 1][0], sA);
      unsigned int b1 = (unsigned int)__shfl((int)W[kc * 2 + 1][1], sA);
      unsigned int b2 = (unsigned int)__shfl((int)W[kc * 2 + 1][0], sB);
      unsigned int b3 = (unsigned int)__shfl((int)W[kc * 2 + 1][1], sB);
      union { unsigned int u[4]; bf16x8 v; } cvt;
      cvt.u[0] = hi ? b0 : a0;
      cvt.u[1] = hi ? b1 : a1;
      cvt.u[2] = hi ? b2 : a2;
      cvt.u[3] = hi ? b3 : a3;
      pa[kc] = cvt.v;
    }

    // PV: accO[q=lh*4+r][hs=l15(+vf*16)] += P * V
#pragma unroll
    for (int kc = 0; kc < 2; ++kc)
#pragma unroll
      for (int vf = 0; vf < 4; ++vf) {
        bf16x8 vt = *reinterpret_cast<const bf16x8*>(&Vl[(vf * 16 + l15) * LST + kc * 32 + lh * 8]);
        accO[vf] = __builtin_amdgcn_mfma_f32_16x16x32_bf16(pa[kc], vt, accO[vf], 0, 0, 0);
      }
    __syncthreads();
  }

  float linv = 1.f / lrun;
  float lr[4];
#pragma unroll
  for (int r = 0; r < 4; ++r) lr[r] = __shfl(linv, lh * 4 + r);
#pragma unroll
  for (int vf = 0; vf < 4; ++vf)
#pragma unroll
    for (int r = 0; r < 4; ++r)
      Op[base + (long)(n0 + w * 16 + lh * 4 + r) * 1024 + vf * 16 + l15] = f2bf(accO[vf][r] * lr[r]);
}

extern "C" void kernel_launch(void* const* d_in, const int* in_sizes, int n_in,
                              void* d_out, int out_size, void* d_ws, size_t ws_size,
                              hipStream_t stream) {
  const float* q    = (const float*)d_in[0];
  const float* k    = (const float*)d_in[1];
  const float* v    = (const float*)d_in[2];
  const float* wq   = (const float*)d_in[3];
  const float* wk   = (const float*)d_in[4];
  const float* wv   = (const float*)d_in[5];
  const float* wp   = (const float*)d_in[6];
  const float* bias = (const float*)d_in[7];

  unsigned short* ws = (unsigned short*)d_ws;
  unsigned short* Wq = ws;
  unsigned short* Wk = Wq + (1 << 20);
  unsigned short* Wv = Wk + (1 << 20);
  unsigned short* Wp = Wv + (1 << 20);
  unsigned short* qp = Wp + (1 << 20);
  unsigned short* kp = qp + (8 << 20);
  unsigned short* vt = kp + (8 << 20);
  unsigned short* mh = vt + (8 << 20);

  pack_wqkv<<<4096, 256, 0, stream>>>(wq, Wq, 0.125f);
  pack_wqkv<<<4096, 256, 0, stream>>>(wk, Wk, 1.0f);
  pack_wqkv<<<4096, 256, 0, stream>>>(wv, Wv, 1.0f);
  pack_wp  <<<4096, 256, 0, stream>>>(wp, Wp);

  dim3 gg(8, 64);
  gemm_k<true, false, false><<<gg, 256, 0, stream>>>(q, Wq, qp, nullptr);
  gemm_k<true, false, false><<<gg, 256, 0, stream>>>(k, Wk, kp, nullptr);
  gemm_k<true, false, true ><<<gg, 256, 0, stream>>>(v, Wv, vt, nullptr);  // -> Vt_g[b][col][m]

  attn_k<<<dim3(32, 64), 256, 0, stream>>>(qp, kp, vt, mh);

  gemm_k<false, true, false><<<gg, 256, 0, stream>>>(mh, Wp, d_out, bias);
}

// Round 3
// 350.665 us; speedup vs baseline: 1.3490x; 1.0540x over previous
//
#include <hip/hip_runtime.h>

typedef __attribute__((ext_vector_type(8))) __bf16 bf16x8;
typedef __attribute__((ext_vector_type(4))) float f32x4;
typedef __attribute__((ext_vector_type(8))) unsigned short u16x8;

__device__ __forceinline__ unsigned short f2bf(float f) {
  unsigned int u = __builtin_bit_cast(unsigned int, f);
  u += 0x7FFFu + ((u >> 16) & 1u);
  return (unsigned short)(u >> 16);
}
// packed f32x2 -> bf16x2 (lo = a, hi = b), single VALU op
__device__ __forceinline__ unsigned int cvtpk(float a, float b) {
  unsigned int r;
  asm("v_cvt_pk_bf16_f32 %0, %1, %2" : "=v"(r) : "v"(a), "v"(b));
  return r;
}

#define KDIM 1024

// ---------- weight packing: out[n][k] = in[h][k][o]*scale, n = h*64+o ----------
__global__ __launch_bounds__(256) void pack_wqkv(const float* __restrict__ w,
                                                 unsigned short* __restrict__ out,
                                                 float scale) {
  int i = blockIdx.x * 256 + threadIdx.x;
  int n = i >> 10, k = i & 1023;
  int h = n >> 6, o = n & 63;
  out[i] = f2bf(w[h * 65536 + k * 64 + o] * scale);
}

__global__ __launch_bounds__(256) void pack_wp(const float* __restrict__ w,
                                               unsigned short* __restrict__ out) {
  int i = blockIdx.x * 256 + threadIdx.x;
  int o = i >> 10, ki = i & 1023;
  out[i] = f2bf(w[ki * 1024 + o]);
}

// ---------- GEMM: C[M][1024] = A[M][1024] x B^T, linear LDS + XOR swizzle ----------
// LDS tile [128][64] bf16 (128B rows). Chunk = 16B. Logical chunk c of row r lives
// at LDS chunk c ^ (r&7). global_load_lds writes linearly -> pre-swizzle the SOURCE.
template <bool AF32, bool OUTF32, bool OUTT>
__global__ __launch_bounds__(256) void gemm_k(const void* __restrict__ Ap,
                                              const unsigned short* __restrict__ Wt,
                                              void* __restrict__ Cp,
                                              const float* __restrict__ bias) {
  __shared__ unsigned short As[128 * 64];
  __shared__ unsigned short Bs[128 * 64];
  const int t = threadIdx.x;
  const int lane = t & 63, w = t >> 6;
  const int wr = (w >> 1) * 64, wc = (w & 1) * 64;
  const int l15 = lane & 15, lh = lane >> 4;
  const int rL = t >> 1;             // fp32-staging row 0..127
  const int c0 = (t & 1) * 32;       // fp32-staging elem offset
  const int rowl = lane >> 3;        // gload_lds: row within 8-row segment
  const int chnk = lane & 7;         // gload_lds: linear LDS chunk
  const long rowA = (long)blockIdx.y * 128 + rL;

  f32x4 acc[4][4];
#pragma unroll
  for (int i = 0; i < 4; ++i)
#pragma unroll
    for (int j = 0; j < 4; ++j) acc[i][j] = {0.f, 0.f, 0.f, 0.f};

  for (int k0 = 0; k0 < KDIM; k0 += 64) {
    if (k0) __syncthreads();
    // ---- B staging: async global->LDS, source pre-swizzled ----
#pragma unroll
    for (int i = 0; i < 4; ++i) {
      const int seg = w * 4 + i;
      const int row = seg * 8 + rowl;
      const unsigned short* src =
          Wt + (long)(blockIdx.x * 128 + row) * KDIM + k0 + ((chnk ^ (row & 7)) * 8);
      __builtin_amdgcn_global_load_lds((const __attribute__((address_space(1))) void*)src,
                                       (__attribute__((address_space(3))) void*)&Bs[seg * 512],
                                       16, 0, 0);
    }
    // ---- A staging ----
    if constexpr (AF32) {
      const float* src = (const float*)Ap + rowA * KDIM + k0 + c0;
      const int chbase = (t & 1) * 4;
#pragma unroll
      for (int e = 0; e < 4; ++e) {
        float4 v0 = *reinterpret_cast<const float4*>(src + e * 8);
        float4 v1 = *reinterpret_cast<const float4*>(src + e * 8 + 4);
        uint4 o;
        o.x = cvtpk(v0.x, v0.y);
        o.y = cvtpk(v0.z, v0.w);
        o.z = cvtpk(v1.x, v1.y);
        o.w = cvtpk(v1.z, v1.w);
        const int ch = (chbase + e) ^ (rL & 7);
        *reinterpret_cast<uint4*>(&As[rL * 64 + ch * 8]) = o;
      }
    } else {
#pragma unroll
      for (int i = 0; i < 4; ++i) {
        const int seg = w * 4 + i;
        const int row = seg * 8 + rowl;
        const unsigned short* src =
            (const unsigned short*)Ap + ((long)blockIdx.y * 128 + row) * KDIM + k0 +
            ((chnk ^ (row & 7)) * 8);
        __builtin_amdgcn_global_load_lds((const __attribute__((address_space(1))) void*)src,
                                         (__attribute__((address_space(3))) void*)&As[seg * 512],
                                         16, 0, 0);
      }
    }
    __syncthreads();   // drains vmcnt -> gload_lds data visible
#pragma unroll
    for (int kc = 0; kc < 2; ++kc) {
      const int chs = ((kc * 4 + lh) ^ (l15 & 7)) * 8;   // swizzled byte-col (in elems)
      bf16x8 af[4], bfr[4];
#pragma unroll
      for (int mi = 0; mi < 4; ++mi)
        af[mi] = *reinterpret_cast<const bf16x8*>(&As[(wr + mi * 16 + l15) * 64 + chs]);
#pragma unroll
      for (int ni = 0; ni < 4; ++ni)
        bfr[ni] = *reinterpret_cast<const bf16x8*>(&Bs[(wc + ni * 16 + l15) * 64 + chs]);
#pragma unroll
      for (int mi = 0; mi < 4; ++mi)
#pragma unroll
        for (int ni = 0; ni < 4; ++ni)
          acc[mi][ni] = __builtin_amdgcn_mfma_f32_16x16x32_bf16(af[mi], bfr[ni], acc[mi][ni], 0, 0, 0);
    }
  }
  const long rbase = (long)blockIdx.y * 128 + wr;
  const long cbase = (long)blockIdx.x * 128 + wc;
#pragma unroll
  for (int ni = 0; ni < 4; ++ni) {
    const long col = cbase + ni * 16 + l15;
    float bv = 0.f;
    if constexpr (OUTF32) bv = bias[col];
#pragma unroll
    for (int mi = 0; mi < 4; ++mi) {
      const long row = rbase + mi * 16 + lh * 4;
      if constexpr (OUTT) {
        // Vt_g[b][col][m]; j-direction (rows) is contiguous in m
        uint2 val;
        val.x = cvtpk(acc[mi][ni][0], acc[mi][ni][1]);
        val.y = cvtpk(acc[mi][ni][2], acc[mi][ni][3]);
        *reinterpret_cast<uint2*>(
            &((unsigned short*)Cp)[(row >> 11) * 2097152 + col * 2048 + (row & 2047)]) = val;
      } else {
#pragma unroll
        for (int j = 0; j < 4; ++j) {
          if constexpr (OUTF32)
            ((float*)Cp)[(row + j) * KDIM + col] = acc[mi][ni][j] + bv;
          else
            ((unsigned short*)Cp)[(row + j) * KDIM + col] = f2bf(acc[mi][ni][j]);
        }
      }
    }
  }
}

// ---------- flash attention, swapped-QK, base-2 softmax, defer-max ----------
__global__ __launch_bounds__(256) void attn_k(const unsigned short* __restrict__ Qp,
                                              const unsigned short* __restrict__ Kp,
                                              const unsigned short* __restrict__ Vtg,
                                              unsigned short* __restrict__ Op) {
  constexpr int LST = 72;
  __shared__ unsigned short Kl[64 * LST];
  __shared__ unsigned short Vl[64 * LST];   // Vl[hs][m]
  const int t = threadIdx.x;
  const int lane = t & 63, w = t >> 6;
  const int l15 = lane & 15, lh = lane >> 4;
  const int bh = blockIdx.y;
  const long base = (long)(bh >> 4) * 2097152 + (long)(bh & 15) * 64;  // [b][n][h*64]
  const long vbase = (long)bh * 131072;                                // [bh][hs][m]
  const int n0 = blockIdx.x * 64;
  const int sr = t >> 2, sc = (t & 3) * 16;

  bf16x8 qf[2];
  {
    const unsigned short* qsrc = Qp + base + (long)(n0 + w * 16 + l15) * 1024 + lh * 8;
    qf[0] = *reinterpret_cast<const bf16x8*>(qsrc);
    qf[1] = *reinterpret_cast<const bf16x8*>(qsrc + 32);
  }

  const unsigned short* ksrc = Kp + base + (long)sr * 1024 + sc;
  const unsigned short* vsrc = Vtg + vbase + (long)sr * 2048 + sc;
  u16x8 kr0 = *reinterpret_cast<const u16x8*>(ksrc);
  u16x8 kr1 = *reinterpret_cast<const u16x8*>(ksrc + 8);
  u16x8 vr0 = *reinterpret_cast<const u16x8*>(vsrc);
  u16x8 vr1 = *reinterpret_cast<const u16x8*>(vsrc + 8);

  float mrun = -3e38f, lrun = 0.f;
  f32x4 accO[4];
#pragma unroll
  for (int vf = 0; vf < 4; ++vf) accO[vf] = {0.f, 0.f, 0.f, 0.f};

  for (int m0 = 0; m0 < 2048; m0 += 64) {
    *reinterpret_cast<u16x8*>(&Kl[sr * LST + sc]) = kr0;
    *reinterpret_cast<u16x8*>(&Kl[sr * LST + sc + 8]) = kr1;
    *reinterpret_cast<u16x8*>(&Vl[sr * LST + sc]) = vr0;
    *reinterpret_cast<u16x8*>(&Vl[sr * LST + sc + 8]) = vr1;
    __syncthreads();
    if (m0 + 64 < 2048) {
      kr0 = *reinterpret_cast<const u16x8*>(ksrc + (long)(m0 + 64) * 1024);
      kr1 = *reinterpret_cast<const u16x8*>(ksrc + (long)(m0 + 64) * 1024 + 8);
      vr0 = *reinterpret_cast<const u16x8*>(vsrc + m0 + 64);
      vr1 = *reinterpret_cast<const u16x8*>(vsrc + m0 + 72);
    }

    // S^T[m][q] in base-2 units (log2e folded into Wq): sp[nf][r], q = l15
    f32x4 sp[4];
#pragma unroll
    for (int nf = 0; nf < 4; ++nf) {
      f32x4 z = {0.f, 0.f, 0.f, 0.f};
      bf16x8 kf0 = *reinterpret_cast<const bf16x8*>(&Kl[(nf * 16 + l15) * LST + lh * 8]);
      bf16x8 kf1 = *reinterpret_cast<const bf16x8*>(&Kl[(nf * 16 + l15) * LST + 32 + lh * 8]);
      z = __builtin_amdgcn_mfma_f32_16x16x32_bf16(kf0, qf[0], z, 0, 0, 0);
      sp[nf] = __builtin_amdgcn_mfma_f32_16x16x32_bf16(kf1, qf[1], z, 0, 0, 0);
    }

    // tile max (per q) + defer-max: only rescale when max grew past threshold
    float mx = fmaxf(fmaxf(sp[0][0], sp[0][1]), fmaxf(sp[0][2], sp[0][3]));
#pragma unroll
    for (int nf = 1; nf < 4; ++nf)
      mx = fmaxf(mx, fmaxf(fmaxf(sp[nf][0], sp[nf][1]), fmaxf(sp[nf][2], sp[nf][3])));
    mx = fmaxf(mx, __shfl_xor(mx, 16));
    mx = fmaxf(mx, __shfl_xor(mx, 32));
    if (!__all(mx <= mrun + 11.5f)) {
      float mnew = fmaxf(mrun, mx);
      float scl = __builtin_amdgcn_exp2f(mrun - mnew);
      lrun *= scl;
#pragma unroll
      for (int r = 0; r < 4; ++r) {
        float sclr = __shfl(scl, lh * 4 + r);
#pragma unroll
        for (int vf = 0; vf < 4; ++vf) accO[vf][r] *= sclr;
      }
      mrun = mnew;
    }

    float p[4][4];
    float ls = 0.f;
#pragma unroll
    for (int nf = 0; nf < 4; ++nf)
#pragma unroll
      for (int r = 0; r < 4; ++r) {
        p[nf][r] = __builtin_amdgcn_exp2f(sp[nf][r] - mrun);
        ls += p[nf][r];
      }
    ls += __shfl_xor(ls, 16);
    ls += __shfl_xor(ls, 32);
    lrun += ls;

    // pack P (v_cvt_pk) and exchange into A-fragment layout
    unsigned int W[4][2];
#pragma unroll
    for (int nf = 0; nf < 4; ++nf) {
      W[nf][0] = cvtpk(p[nf][0], p[nf][1]);
      W[nf][1] = cvtpk(p[nf][2], p[nf][3]);
    }
    const int sA = (lh & 1) * 32 + l15;
    const int sB = sA + 16;
    const bool hi = lh >= 2;
    bf16x8 pa[2];
#pragma unroll
    for (int kc = 0; kc < 2; ++kc) {
      unsigned int a0 = (unsigned int)__shfl((int)W[kc * 2][0], sA);
      unsigned int a1 = (unsigned int)__shfl((int)W[kc * 2][1], sA);
      unsigned int a2 = (unsigned int)__shfl((int)W[kc * 2][0], sB);
      unsigned int a3 = (unsigned int)__shfl((int)W[kc * 2][1], sB);
      unsigned int b0 = (unsigned int)__shfl((int)W[kc * 2 + 1][0], sA);
      unsigned int b1 = (unsigned int)__shfl((int)W[kc * 2 + 1][1], sA);
      unsigned int b2 = (unsigned int)__shfl((int)W[kc * 2 + 1][0], sB);
      unsigned int b3 = (unsigned int)__shfl((int)W[kc * 2 + 1][1], sB);
      union { unsigned int u[4]; bf16x8 v; } cvt;
      cvt.u[0] = hi ? b0 : a0;
      cvt.u[1] = hi ? b1 : a1;
      cvt.u[2] = hi ? b2 : a2;
      cvt.u[3] = hi ? b3 : a3;
      pa[kc] = cvt.v;
    }

#pragma unroll
    for (int kc = 0; kc < 2; ++kc)
#pragma unroll
      for (int vf = 0; vf < 4; ++vf) {
        bf16x8 vt = *reinterpret_cast<const bf16x8*>(&Vl[(vf * 16 + l15) * LST + kc * 32 + lh * 8]);
        accO[vf] = __builtin_amdgcn_mfma_f32_16x16x32_bf16(pa[kc], vt, accO[vf], 0, 0, 0);
      }
    __syncthreads();
  }

  float linv = 1.f / lrun;
  float lr[4];
#pragma unroll
  for (int r = 0; r < 4; ++r) lr[r] = __shfl(linv, lh * 4 + r);
#pragma unroll
  for (int vf = 0; vf < 4; ++vf)
#pragma unroll
    for (int r = 0; r < 4; ++r)
      Op[base + (long)(n0 + w * 16 + lh * 4 + r) * 1024 + vf * 16 + l15] = f2bf(accO[vf][r] * lr[r]);
}

extern "C" void kernel_launch(void* const* d_in, const int* in_sizes, int n_in,
                              void* d_out, int out_size, void* d_ws, size_t ws_size,
                              hipStream_t stream) {
  const float* q    = (const float*)d_in[0];
  const float* k    = (const float*)d_in[1];
  const float* v    = (const float*)d_in[2];
  const float* wq   = (const float*)d_in[3];
  const float* wk   = (const float*)d_in[4];
  const float* wv   = (const float*)d_in[5];
  const float* wp   = (const float*)d_in[6];
  const float* bias = (const float*)d_in[7];

  unsigned short* ws = (unsigned short*)d_ws;
  unsigned short* Wq = ws;
  unsigned short* Wk = Wq + (1 << 20);
  unsigned short* Wv = Wk + (1 << 20);
  unsigned short* Wp = Wv + (1 << 20);
  unsigned short* qp = Wp + (1 << 20);
  unsigned short* kp = qp + (8 << 20);
  unsigned short* vt = kp + (8 << 20);
  unsigned short* mh = vt + (8 << 20);

  // fold 1/sqrt(64) * log2(e) into Wq -> softmax runs in base 2
  pack_wqkv<<<4096, 256, 0, stream>>>(wq, Wq, 0.125f * 1.44269504089f);
  pack_wqkv<<<4096, 256, 0, stream>>>(wk, Wk, 1.0f);
  pack_wqkv<<<4096, 256, 0, stream>>>(wv, Wv, 1.0f);
  pack_wp  <<<4096, 256, 0, stream>>>(wp, Wp);

  dim3 gg(8, 64);
  gemm_k<true, false, false><<<gg, 256, 0, stream>>>(q, Wq, qp, nullptr);
  gemm_k<true, false, false><<<gg, 256, 0, stream>>>(k, Wk, kp, nullptr);
  gemm_k<true, false, true ><<<gg, 256, 0, stream>>>(v, Wv, vt, nullptr);  // -> Vt_g[b][col][m]

  attn_k<<<dim3(32, 64), 256, 0, stream>>>(qp, kp, vt, mh);

  gemm_k<false, true, false><<<gg, 256, 0, stream>>>(mh, Wp, d_out, bias);
}

// Round 5
// 322.918 us; speedup vs baseline: 1.4649x; 1.0859x over previous
//
#include <hip/hip_runtime.h>

typedef __attribute__((ext_vector_type(8))) __bf16 bf16x8;
typedef __attribute__((ext_vector_type(4))) float f32x4;
typedef __attribute__((ext_vector_type(8))) unsigned short u16x8;

__device__ __forceinline__ unsigned short f2bf(float f) {
  unsigned int u = __builtin_bit_cast(unsigned int, f);
  u += 0x7FFFu + ((u >> 16) & 1u);
  return (unsigned short)(u >> 16);
}
// packed f32x2 -> bf16x2 (lo = a, hi = b), single VALU op
__device__ __forceinline__ unsigned int cvtpk(float a, float b) {
  unsigned int r;
  asm("v_cvt_pk_bf16_f32 %0, %1, %2" : "=v"(r) : "v"(a), "v"(b));
  return r;
}

#define KDIM 1024

// ---------- weight packing via LDS transpose (coalesced both sides) ----------
// out[n][k] = w[h][k][o]*scale, n = h*64+o. One block per (h, 64-wide k tile).
__global__ __launch_bounds__(256) void pack_wqkv(const float* __restrict__ w,
                                                 unsigned short* __restrict__ out,
                                                 float scale) {
  __shared__ float T[64][68];
  const int h = blockIdx.x >> 4;
  const int k0 = (blockIdx.x & 15) * 64;
  const int t = threadIdx.x;
  const int r = t >> 2, c0 = (t & 3) * 16;
  const float* src = w + h * 65536 + (k0 + r) * 64 + c0;
#pragma unroll
  for (int e = 0; e < 16; e += 4)
    *reinterpret_cast<float4*>(&T[r][c0 + e]) = *reinterpret_cast<const float4*>(src + e);
  __syncthreads();
  unsigned int pk[8];
#pragma unroll
  for (int e = 0; e < 8; ++e)
    pk[e] = cvtpk(T[c0 + 2 * e][r] * scale, T[c0 + 2 * e + 1][r] * scale);
  unsigned short* dst = out + (h * 64 + r) * 1024 + k0 + c0;
  *reinterpret_cast<uint4*>(dst) = *reinterpret_cast<uint4*>(pk);
  *reinterpret_cast<uint4*>(dst + 8) = *reinterpret_cast<uint4*>(pk + 4);
}

// out[o][ki] = w[ki][o] (1024x1024 transpose), blocks over (ki tile, o tile)
__global__ __launch_bounds__(256) void pack_wp(const float* __restrict__ w,
                                               unsigned short* __restrict__ out) {
  __shared__ float T[64][68];
  const int i0 = (blockIdx.x >> 4) * 64;   // ki
  const int o0 = (blockIdx.x & 15) * 64;   // o
  const int t = threadIdx.x;
  const int r = t >> 2, c0 = (t & 3) * 16;
  const float* src = w + (long)(i0 + r) * 1024 + o0 + c0;
#pragma unroll
  for (int e = 0; e < 16; e += 4)
    *reinterpret_cast<float4*>(&T[r][c0 + e]) = *reinterpret_cast<const float4*>(src + e);
  __syncthreads();
  unsigned int pk[8];
#pragma unroll
  for (int e = 0; e < 8; ++e)
    pk[e] = cvtpk(T[c0 + 2 * e][r], T[c0 + 2 * e + 1][r]);
  unsigned short* dst = out + (long)(o0 + r) * 1024 + i0 + c0;
  *reinterpret_cast<uint4*>(dst) = *reinterpret_cast<uint4*>(pk);
  *reinterpret_cast<uint4*>(dst + 8) = *reinterpret_cast<uint4*>(pk + 4);
}

// ---------- GEMM: C[M][1024] = A[M][1024] x B^T, BM=64 BN=128 BK=64 ----------
// LDS tiles [rows][64] bf16, 16B chunk c of row r stored at chunk c^(r&7).
// global_load_lds writes linearly -> pre-swizzle the global SOURCE address.
template <bool AF32, bool OUTF32, bool OUTT>
__global__ __launch_bounds__(256) void gemm_k(const void* __restrict__ Ap,
                                              const unsigned short* __restrict__ Wt,
                                              void* __restrict__ Cp,
                                              const float* __restrict__ bias) {
  __shared__ unsigned short As[64 * 64];
  __shared__ unsigned short Bs[128 * 64];
  const int t = threadIdx.x;
  const int lane = t & 63, w = t >> 6;
  const int wr = (w >> 1) * 32, wc = (w & 1) * 64;
  const int l15 = lane & 15, lh = lane >> 4;
  const int rowl = lane >> 3;        // gload_lds: row within 8-row segment
  const int chnk = lane & 7;         // gload_lds: linear LDS chunk

  f32x4 acc[2][4];
#pragma unroll
  for (int i = 0; i < 2; ++i)
#pragma unroll
    for (int j = 0; j < 4; ++j) acc[i][j] = {0.f, 0.f, 0.f, 0.f};

  for (int k0 = 0; k0 < KDIM; k0 += 64) {
    if (k0) __syncthreads();
    // ---- B staging: 128 rows = 16 segments, async global->LDS ----
#pragma unroll
    for (int i = 0; i < 4; ++i) {
      const int seg = w * 4 + i;
      const int row = seg * 8 + rowl;
      const unsigned short* src =
          Wt + (long)(blockIdx.x * 128 + row) * KDIM + k0 + ((chnk ^ (row & 7)) * 8);
      __builtin_amdgcn_global_load_lds((const __attribute__((address_space(1))) void*)src,
                                       (__attribute__((address_space(3))) void*)&Bs[seg * 512],
                                       16, 0, 0);
    }
    // ---- A staging: 64 rows ----
    if constexpr (AF32) {
      const int rL = t >> 2, cb = (t & 3) * 16;
      const float* src = (const float*)Ap + ((long)blockIdx.y * 64 + rL) * KDIM + k0 + cb;
      float4 v0 = *reinterpret_cast<const float4*>(src);
      float4 v1 = *reinterpret_cast<const float4*>(src + 4);
      float4 v2 = *reinterpret_cast<const float4*>(src + 8);
      float4 v3 = *reinterpret_cast<const float4*>(src + 12);
      uint4 o0, o1;
      o0.x = cvtpk(v0.x, v0.y); o0.y = cvtpk(v0.z, v0.w);
      o0.z = cvtpk(v1.x, v1.y); o0.w = cvtpk(v1.z, v1.w);
      o1.x = cvtpk(v2.x, v2.y); o1.y = cvtpk(v2.z, v2.w);
      o1.z = cvtpk(v3.x, v3.y); o1.w = cvtpk(v3.z, v3.w);
      const int chl = (t & 3) * 2;
      *reinterpret_cast<uint4*>(&As[rL * 64 + ((chl) ^ (rL & 7)) * 8]) = o0;
      *reinterpret_cast<uint4*>(&As[rL * 64 + ((chl + 1) ^ (rL & 7)) * 8]) = o1;
    } else {
#pragma unroll
      for (int i = 0; i < 2; ++i) {
        const int seg = w * 2 + i;
        const int row = seg * 8 + rowl;
        const unsigned short* src =
            (const unsigned short*)Ap + ((long)blockIdx.y * 64 + row) * KDIM + k0 +
            ((chnk ^ (row & 7)) * 8);
        __builtin_amdgcn_global_load_lds((const __attribute__((address_space(1))) void*)src,
                                         (__attribute__((address_space(3))) void*)&As[seg * 512],
                                         16, 0, 0);
      }
    }
    __syncthreads();
#pragma unroll
    for (int kc = 0; kc < 2; ++kc) {
      const int chs = ((kc * 4 + lh) ^ (l15 & 7)) * 8;
      bf16x8 af[2], bfr[4];
#pragma unroll
      for (int mi = 0; mi < 2; ++mi)
        af[mi] = *reinterpret_cast<const bf16x8*>(&As[(wr + mi * 16 + l15) * 64 + chs]);
#pragma unroll
      for (int ni = 0; ni < 4; ++ni)
        bfr[ni] = *reinterpret_cast<const bf16x8*>(&Bs[(wc + ni * 16 + l15) * 64 + chs]);
#pragma unroll
      for (int mi = 0; mi < 2; ++mi)
#pragma unroll
        for (int ni = 0; ni < 4; ++ni)
          acc[mi][ni] = __builtin_amdgcn_mfma_f32_16x16x32_bf16(af[mi], bfr[ni], acc[mi][ni], 0, 0, 0);
    }
  }
  const long rbase = (long)blockIdx.y * 64 + wr;
  const long cbase = (long)blockIdx.x * 128 + wc;
#pragma unroll
  for (int ni = 0; ni < 4; ++ni) {
    const long col = cbase + ni * 16 + l15;
    float bv = 0.f;
    if constexpr (OUTF32) bv = bias[col];
#pragma unroll
    for (int mi = 0; mi < 2; ++mi) {
      const long row = rbase + mi * 16 + lh * 4;
      if constexpr (OUTT) {
        uint2 val;
        val.x = cvtpk(acc[mi][ni][0], acc[mi][ni][1]);
        val.y = cvtpk(acc[mi][ni][2], acc[mi][ni][3]);
        *reinterpret_cast<uint2*>(
            &((unsigned short*)Cp)[(row >> 11) * 2097152 + col * 2048 + (row & 2047)]) = val;
      } else {
#pragma unroll
        for (int j = 0; j < 4; ++j) {
          if constexpr (OUTF32)
            ((float*)Cp)[(row + j) * KDIM + col] = acc[mi][ni][j] + bv;
          else
            ((unsigned short*)Cp)[(row + j) * KDIM + col] = f2bf(acc[mi][ni][j]);
        }
      }
    }
  }
}

// ---------- flash attention, swapped-QK, base-2 softmax, defer-max ----------
// PROVEN round-2 structure: single KV buffer, stage->barrier->compute->barrier.
__global__ __launch_bounds__(256) void attn_k(const unsigned short* __restrict__ Qp,
                                              const unsigned short* __restrict__ Kp,
                                              const unsigned short* __restrict__ Vtg,
                                              unsigned short* __restrict__ Op) {
  constexpr int LST = 72;
  __shared__ unsigned short Kl[64 * LST];
  __shared__ unsigned short Vl[64 * LST];   // Vl[hs][m]
  const int t = threadIdx.x;
  const int lane = t & 63, w = t >> 6;
  const int l15 = lane & 15, lh = lane >> 4;
  const int bh = blockIdx.y;
  const long base = (long)(bh >> 4) * 2097152 + (long)(bh & 15) * 64;  // [b][n][h*64]
  const long vbase = (long)bh * 131072;                                // [bh][hs][m]
  const int n0 = blockIdx.x * 64;
  const int sr = t >> 2, sc = (t & 3) * 16;

  bf16x8 qf[2];
  {
    const unsigned short* qsrc = Qp + base + (long)(n0 + w * 16 + l15) * 1024 + lh * 8;
    qf[0] = *reinterpret_cast<const bf16x8*>(qsrc);
    qf[1] = *reinterpret_cast<const bf16x8*>(qsrc + 32);
  }

  const unsigned short* ksrc = Kp + base + (long)sr * 1024 + sc;
  const unsigned short* vsrc = Vtg + vbase + (long)sr * 2048 + sc;
  u16x8 kr0 = *reinterpret_cast<const u16x8*>(ksrc);
  u16x8 kr1 = *reinterpret_cast<const u16x8*>(ksrc + 8);
  u16x8 vr0 = *reinterpret_cast<const u16x8*>(vsrc);
  u16x8 vr1 = *reinterpret_cast<const u16x8*>(vsrc + 8);

  float mrun = -3e38f, lrun = 0.f;
  f32x4 accO[4];
#pragma unroll
  for (int vf = 0; vf < 4; ++vf) accO[vf] = {0.f, 0.f, 0.f, 0.f};

  for (int m0 = 0; m0 < 2048; m0 += 64) {
    *reinterpret_cast<u16x8*>(&Kl[sr * LST + sc]) = kr0;
    *reinterpret_cast<u16x8*>(&Kl[sr * LST + sc + 8]) = kr1;
    *reinterpret_cast<u16x8*>(&Vl[sr * LST + sc]) = vr0;
    *reinterpret_cast<u16x8*>(&Vl[sr * LST + sc + 8]) = vr1;
    __syncthreads();
    if (m0 + 64 < 2048) {
      kr0 = *reinterpret_cast<const u16x8*>(ksrc + (long)(m0 + 64) * 1024);
      kr1 = *reinterpret_cast<const u16x8*>(ksrc + (long)(m0 + 64) * 1024 + 8);
      vr0 = *reinterpret_cast<const u16x8*>(vsrc + m0 + 64);
      vr1 = *reinterpret_cast<const u16x8*>(vsrc + m0 + 72);
    }

    // S^T[m][q] in base-2 units (log2e folded into Wq): sp[nf][r], q = l15
    f32x4 sp[4];
    __builtin_amdgcn_s_setprio(1);
#pragma unroll
    for (int nf = 0; nf < 4; ++nf) {
      f32x4 z = {0.f, 0.f, 0.f, 0.f};
      bf16x8 kf0 = *reinterpret_cast<const bf16x8*>(&Kl[(nf * 16 + l15) * LST + lh * 8]);
      bf16x8 kf1 = *reinterpret_cast<const bf16x8*>(&Kl[(nf * 16 + l15) * LST + 32 + lh * 8]);
      z = __builtin_amdgcn_mfma_f32_16x16x32_bf16(kf0, qf[0], z, 0, 0, 0);
      sp[nf] = __builtin_amdgcn_mfma_f32_16x16x32_bf16(kf1, qf[1], z, 0, 0, 0);
    }
    __builtin_amdgcn_s_setprio(0);

    // tile max (per q) + defer-max: only rescale when max grew past threshold
    float mx = fmaxf(fmaxf(sp[0][0], sp[0][1]), fmaxf(sp[0][2], sp[0][3]));
#pragma unroll
    for (int nf = 1; nf < 4; ++nf)
      mx = fmaxf(mx, fmaxf(fmaxf(sp[nf][0], sp[nf][1]), fmaxf(sp[nf][2], sp[nf][3])));
    mx = fmaxf(mx, __shfl_xor(mx, 16));
    mx = fmaxf(mx, __shfl_xor(mx, 32));
    if (!__all(mx <= mrun + 11.5f)) {
      float mnew = fmaxf(mrun, mx);
      float scl = __builtin_amdgcn_exp2f(mrun - mnew);
      lrun *= scl;
#pragma unroll
      for (int r = 0; r < 4; ++r) {
        float sclr = __shfl(scl, lh * 4 + r);
#pragma unroll
        for (int vf = 0; vf < 4; ++vf) accO[vf][r] *= sclr;
      }
      mrun = mnew;
    }

    float p[4][4];
    float ls = 0.f;
#pragma unroll
    for (int nf = 0; nf < 4; ++nf)
#pragma unroll
      for (int r = 0; r < 4; ++r) {
        p[nf][r] = __builtin_amdgcn_exp2f(sp[nf][r] - mrun);
        ls += p[nf][r];
      }
    ls += __shfl_xor(ls, 16);
    ls += __shfl_xor(ls, 32);
    lrun += ls;

    // pack P (v_cvt_pk) and exchange into A-fragment layout
    unsigned int W[4][2];
#pragma unroll
    for (int nf = 0; nf < 4; ++nf) {
      W[nf][0] = cvtpk(p[nf][0], p[nf][1]);
      W[nf][1] = cvtpk(p[nf][2], p[nf][3]);
    }
    const int sA = (lh & 1) * 32 + l15;
    const int sB = sA + 16;
    const bool hi = lh >= 2;
    bf16x8 pa[2];
#pragma unroll
    for (int kc = 0; kc < 2; ++kc) {
      unsigned int a0 = (unsigned int)__shfl((int)W[kc * 2][0], sA);
      unsigned int a1 = (unsigned int)__shfl((int)W[kc * 2][1], sA);
      unsigned int a2 = (unsigned int)__shfl((int)W[kc * 2][0], sB);
      unsigned int a3 = (unsigned int)__shfl((int)W[kc * 2][1], sB);
      unsigned int b0 = (unsigned int)__shfl((int)W[kc * 2 + 1][0], sA);
      unsigned int b1 = (unsigned int)__shfl((int)W[kc * 2 + 1][1], sA);
      unsigned int b2 = (unsigned int)__shfl((int)W[kc * 2 + 1][0], sB);
      unsigned int b3 = (unsigned int)__shfl((int)W[kc * 2 + 1][1], sB);
      union { unsigned int u[4]; bf16x8 v; } cvt;
      cvt.u[0] = hi ? b0 : a0;
      cvt.u[1] = hi ? b1 : a1;
      cvt.u[2] = hi ? b2 : a2;
      cvt.u[3] = hi ? b3 : a3;
      pa[kc] = cvt.v;
    }

    __builtin_amdgcn_s_setprio(1);
#pragma unroll
    for (int kc = 0; kc < 2; ++kc)
#pragma unroll
      for (int vf = 0; vf < 4; ++vf) {
        bf16x8 vt = *reinterpret_cast<const bf16x8*>(&Vl[(vf * 16 + l15) * LST + kc * 32 + lh * 8]);
        accO[vf] = __builtin_amdgcn_mfma_f32_16x16x32_bf16(pa[kc], vt, accO[vf], 0, 0, 0);
      }
    __builtin_amdgcn_s_setprio(0);
    __syncthreads();
  }

  float linv = 1.f / lrun;
  float lr[4];
#pragma unroll
  for (int r = 0; r < 4; ++r) lr[r] = __shfl(linv, lh * 4 + r);
#pragma unroll
  for (int vf = 0; vf < 4; ++vf)
#pragma unroll
    for (int r = 0; r < 4; ++r)
      Op[base + (long)(n0 + w * 16 + lh * 4 + r) * 1024 + vf * 16 + l15] = f2bf(accO[vf][r] * lr[r]);
}

extern "C" void kernel_launch(void* const* d_in, const int* in_sizes, int n_in,
                              void* d_out, int out_size, void* d_ws, size_t ws_size,
                              hipStream_t stream) {
  const float* q    = (const float*)d_in[0];
  const float* k    = (const float*)d_in[1];
  const float* v    = (const float*)d_in[2];
  const float* wq   = (const float*)d_in[3];
  const float* wk   = (const float*)d_in[4];
  const float* wv   = (const float*)d_in[5];
  const float* wp   = (const float*)d_in[6];
  const float* bias = (const float*)d_in[7];

  unsigned short* ws = (unsigned short*)d_ws;
  unsigned short* Wq = ws;
  unsigned short* Wk = Wq + (1 << 20);
  unsigned short* Wv = Wk + (1 << 20);
  unsigned short* Wp = Wv + (1 << 20);
  unsigned short* qp = Wp + (1 << 20);
  unsigned short* kp = qp + (8 << 20);
  unsigned short* vt = kp + (8 << 20);
  unsigned short* mh = vt + (8 << 20);

  // fold 1/sqrt(64) * log2(e) into Wq -> softmax runs in base 2
  pack_wqkv<<<256, 256, 0, stream>>>(wq, Wq, 0.125f * 1.44269504089f);
  pack_wqkv<<<256, 256, 0, stream>>>(wk, Wk, 1.0f);
  pack_wqkv<<<256, 256, 0, stream>>>(wv, Wv, 1.0f);
  pack_wp  <<<256, 256, 0, stream>>>(wp, Wp);

  dim3 gg(8, 128);  // (1024/128 col tiles, 8192/64 row tiles)
  gemm_k<true, false, false><<<gg, 256, 0, stream>>>(q, Wq, qp, nullptr);
  gemm_k<true, false, false><<<gg, 256, 0, stream>>>(k, Wk, kp, nullptr);
  gemm_k<true, false, true ><<<gg, 256, 0, stream>>>(v, Wv, vt, nullptr);  // -> Vt_g[b][col][m]

  attn_k<<<dim3(32, 64), 256, 0, stream>>>(qp, kp, vt, mh);

  gemm_k<false, true, false><<<gg, 256, 0, stream>>>(mh, Wp, d_out, bias);
}

// Round 6
// 282.044 us; speedup vs baseline: 1.6772x; 1.1449x over previous
//
#include <hip/hip_runtime.h>

typedef __attribute__((ext_vector_type(8))) __bf16 bf16x8;
typedef __attribute__((ext_vector_type(4))) float f32x4;
typedef __attribute__((ext_vector_type(16))) float f32x16;
typedef __attribute__((ext_vector_type(8))) unsigned short u16x8;

__device__ __forceinline__ unsigned short f2bf(float f) {
  unsigned int u = __builtin_bit_cast(unsigned int, f);
  u += 0x7FFFu + ((u >> 16) & 1u);
  return (unsigned short)(u >> 16);
}
// packed f32x2 -> bf16x2 (lo = a, hi = b), single VALU op
__device__ __forceinline__ unsigned int cvtpk(float a, float b) {
  unsigned int r;
  asm("v_cvt_pk_bf16_f32 %0, %1, %2" : "=v"(r) : "v"(a), "v"(b));
  return r;
}

#define KDIM 1024

// ---------- weight packing via LDS transpose (coalesced both sides) ----------
__global__ __launch_bounds__(256) void pack_wqkv(const float* __restrict__ w,
                                                 unsigned short* __restrict__ out,
                                                 float scale) {
  __shared__ float T[64][68];
  const int h = blockIdx.x >> 4;
  const int k0 = (blockIdx.x & 15) * 64;
  const int t = threadIdx.x;
  const int r = t >> 2, c0 = (t & 3) * 16;
  const float* src = w + h * 65536 + (k0 + r) * 64 + c0;
#pragma unroll
  for (int e = 0; e < 16; e += 4)
    *reinterpret_cast<float4*>(&T[r][c0 + e]) = *reinterpret_cast<const float4*>(src + e);
  __syncthreads();
  unsigned int pk[8];
#pragma unroll
  for (int e = 0; e < 8; ++e)
    pk[e] = cvtpk(T[c0 + 2 * e][r] * scale, T[c0 + 2 * e + 1][r] * scale);
  unsigned short* dst = out + (h * 64 + r) * 1024 + k0 + c0;
  *reinterpret_cast<uint4*>(dst) = *reinterpret_cast<uint4*>(pk);
  *reinterpret_cast<uint4*>(dst + 8) = *reinterpret_cast<uint4*>(pk + 4);
}

__global__ __launch_bounds__(256) void pack_wp(const float* __restrict__ w,
                                               unsigned short* __restrict__ out) {
  __shared__ float T[64][68];
  const int i0 = (blockIdx.x >> 4) * 64;   // ki
  const int o0 = (blockIdx.x & 15) * 64;   // o
  const int t = threadIdx.x;
  const int r = t >> 2, c0 = (t & 3) * 16;
  const float* src = w + (long)(i0 + r) * 1024 + o0 + c0;
#pragma unroll
  for (int e = 0; e < 16; e += 4)
    *reinterpret_cast<float4*>(&T[r][c0 + e]) = *reinterpret_cast<const float4*>(src + e);
  __syncthreads();
  unsigned int pk[8];
#pragma unroll
  for (int e = 0; e < 8; ++e)
    pk[e] = cvtpk(T[c0 + 2 * e][r], T[c0 + 2 * e + 1][r]);
  unsigned short* dst = out + (long)(o0 + r) * 1024 + i0 + c0;
  *reinterpret_cast<uint4*>(dst) = *reinterpret_cast<uint4*>(pk);
  *reinterpret_cast<uint4*>(dst + 8) = *reinterpret_cast<uint4*>(pk + 4);
}

// ---------- GEMM: C[M][1024] = A[M][1024] x B^T, BM=64 BN=128 BK=64 ----------
template <bool AF32, bool OUTF32, bool OUTT>
__global__ __launch_bounds__(256) void gemm_k(const void* __restrict__ Ap,
                                              const unsigned short* __restrict__ Wt,
                                              void* __restrict__ Cp,
                                              const float* __restrict__ bias) {
  __shared__ unsigned short As[64 * 64];
  __shared__ unsigned short Bs[128 * 64];
  const int t = threadIdx.x;
  const int lane = t & 63, w = t >> 6;
  const int wr = (w >> 1) * 32, wc = (w & 1) * 64;
  const int l15 = lane & 15, lh = lane >> 4;
  const int rowl = lane >> 3;
  const int chnk = lane & 7;

  f32x4 acc[2][4];
#pragma unroll
  for (int i = 0; i < 2; ++i)
#pragma unroll
    for (int j = 0; j < 4; ++j) acc[i][j] = {0.f, 0.f, 0.f, 0.f};

  for (int k0 = 0; k0 < KDIM; k0 += 64) {
    if (k0) __syncthreads();
#pragma unroll
    for (int i = 0; i < 4; ++i) {
      const int seg = w * 4 + i;
      const int row = seg * 8 + rowl;
      const unsigned short* src =
          Wt + (long)(blockIdx.x * 128 + row) * KDIM + k0 + ((chnk ^ (row & 7)) * 8);
      __builtin_amdgcn_global_load_lds((const __attribute__((address_space(1))) void*)src,
                                       (__attribute__((address_space(3))) void*)&Bs[seg * 512],
                                       16, 0, 0);
    }
    if constexpr (AF32) {
      const int rL = t >> 2, cb = (t & 3) * 16;
      const float* src = (const float*)Ap + ((long)blockIdx.y * 64 + rL) * KDIM + k0 + cb;
      float4 v0 = *reinterpret_cast<const float4*>(src);
      float4 v1 = *reinterpret_cast<const float4*>(src + 4);
      float4 v2 = *reinterpret_cast<const float4*>(src + 8);
      float4 v3 = *reinterpret_cast<const float4*>(src + 12);
      uint4 o0, o1;
      o0.x = cvtpk(v0.x, v0.y); o0.y = cvtpk(v0.z, v0.w);
      o0.z = cvtpk(v1.x, v1.y); o0.w = cvtpk(v1.z, v1.w);
      o1.x = cvtpk(v2.x, v2.y); o1.y = cvtpk(v2.z, v2.w);
      o1.z = cvtpk(v3.x, v3.y); o1.w = cvtpk(v3.z, v3.w);
      const int chl = (t & 3) * 2;
      *reinterpret_cast<uint4*>(&As[rL * 64 + ((chl) ^ (rL & 7)) * 8]) = o0;
      *reinterpret_cast<uint4*>(&As[rL * 64 + ((chl + 1) ^ (rL & 7)) * 8]) = o1;
    } else {
#pragma unroll
      for (int i = 0; i < 2; ++i) {
        const int seg = w * 2 + i;
        const int row = seg * 8 + rowl;
        const unsigned short* src =
            (const unsigned short*)Ap + ((long)blockIdx.y * 64 + row) * KDIM + k0 +
            ((chnk ^ (row & 7)) * 8);
        __builtin_amdgcn_global_load_lds((const __attribute__((address_space(1))) void*)src,
                                         (__attribute__((address_space(3))) void*)&As[seg * 512],
                                         16, 0, 0);
      }
    }
    __syncthreads();
#pragma unroll
    for (int kc = 0; kc < 2; ++kc) {
      const int chs = ((kc * 4 + lh) ^ (l15 & 7)) * 8;
      bf16x8 af[2], bfr[4];
#pragma unroll
      for (int mi = 0; mi < 2; ++mi)
        af[mi] = *reinterpret_cast<const bf16x8*>(&As[(wr + mi * 16 + l15) * 64 + chs]);
#pragma unroll
      for (int ni = 0; ni < 4; ++ni)
        bfr[ni] = *reinterpret_cast<const bf16x8*>(&Bs[(wc + ni * 16 + l15) * 64 + chs]);
#pragma unroll
      for (int mi = 0; mi < 2; ++mi)
#pragma unroll
        for (int ni = 0; ni < 4; ++ni)
          acc[mi][ni] = __builtin_amdgcn_mfma_f32_16x16x32_bf16(af[mi], bfr[ni], acc[mi][ni], 0, 0, 0);
    }
  }
  const long rbase = (long)blockIdx.y * 64 + wr;
  const long cbase = (long)blockIdx.x * 128 + wc;
#pragma unroll
  for (int ni = 0; ni < 4; ++ni) {
    const long col = cbase + ni * 16 + l15;
    float bv = 0.f;
    if constexpr (OUTF32) bv = bias[col];
#pragma unroll
    for (int mi = 0; mi < 2; ++mi) {
      const long row = rbase + mi * 16 + lh * 4;
      if constexpr (OUTT) {
        uint2 val;
        val.x = cvtpk(acc[mi][ni][0], acc[mi][ni][1]);
        val.y = cvtpk(acc[mi][ni][2], acc[mi][ni][3]);
        *reinterpret_cast<uint2*>(
            &((unsigned short*)Cp)[(row >> 11) * 2097152 + col * 2048 + (row & 2047)]) = val;
      } else {
#pragma unroll
        for (int j = 0; j < 4; ++j) {
          if constexpr (OUTF32)
            ((float*)Cp)[(row + j) * KDIM + col] = acc[mi][ni][j] + bv;
          else
            ((unsigned short*)Cp)[(row + j) * KDIM + col] = f2bf(acc[mi][ni][j]);
        }
      }
    }
  }
}

// ---------- flash attention: 32x32 MFMA, swapped-QK, lane-local softmax ----------
// 4 warps x QBLK=32 q-rows (block = 128 q), KVBLK=64. grid (2048/128, B*H).
// S^T tile = mfma(K_frag, Q^T_frag): lane holds S[m][q=l&31] for 16 m-rows/tile.
// C/D layout (verified): col=l&31, row=(r&3)+8*(r>>2)+4*(l>>5).
__global__ __launch_bounds__(256) void attn_k(const unsigned short* __restrict__ Qp,
                                              const unsigned short* __restrict__ Kp,
                                              const unsigned short* __restrict__ Vtg,
                                              unsigned short* __restrict__ Op) {
  constexpr int LST = 72;
  __shared__ unsigned short Kl[64 * LST];
  __shared__ unsigned short Vl[64 * LST];   // Vl[hs][m]
  const int t = threadIdx.x;
  const int lane = t & 63, w = t >> 6;
  const int l31 = lane & 31;
  const int hi = lane >> 5;
  const int bh = blockIdx.y;
  const long base = (long)(bh >> 4) * 2097152 + (long)(bh & 15) * 64;  // [b][n][h*64]
  const long vbase = (long)bh * 131072;                                // [bh][hs][m]
  const int n0 = blockIdx.x * 128;
  const int sr = t >> 2, sc = (t & 3) * 16;

  // Q B-frags: qb[kc] = Q[n0 + w*32 + l31][kc*16 + hi*8 .. +8]
  bf16x8 qb[4];
  {
    const unsigned short* qsrc = Qp + base + (long)(n0 + w * 32 + l31) * 1024 + hi * 8;
#pragma unroll
    for (int kc = 0; kc < 4; ++kc)
      qb[kc] = *reinterpret_cast<const bf16x8*>(qsrc + kc * 16);
  }

  const unsigned short* ksrc = Kp + base + (long)sr * 1024 + sc;
  const unsigned short* vsrc = Vtg + vbase + (long)sr * 2048 + sc;
  u16x8 kr0 = *reinterpret_cast<const u16x8*>(ksrc);
  u16x8 kr1 = *reinterpret_cast<const u16x8*>(ksrc + 8);
  u16x8 vr0 = *reinterpret_cast<const u16x8*>(vsrc);
  u16x8 vr1 = *reinterpret_cast<const u16x8*>(vsrc + 8);

  float mrun = -3e38f, lsum = 0.f;
  f32x16 accO0, accO1;
#pragma unroll
  for (int r = 0; r < 16; ++r) { accO0[r] = 0.f; accO1[r] = 0.f; }

  for (int m0 = 0; m0 < 2048; m0 += 64) {
    *reinterpret_cast<u16x8*>(&Kl[sr * LST + sc]) = kr0;
    *reinterpret_cast<u16x8*>(&Kl[sr * LST + sc + 8]) = kr1;
    *reinterpret_cast<u16x8*>(&Vl[sr * LST + sc]) = vr0;
    *reinterpret_cast<u16x8*>(&Vl[sr * LST + sc + 8]) = vr1;
    __syncthreads();
    if (m0 + 64 < 2048) {
      kr0 = *reinterpret_cast<const u16x8*>(ksrc + (long)(m0 + 64) * 1024);
      kr1 = *reinterpret_cast<const u16x8*>(ksrc + (long)(m0 + 64) * 1024 + 8);
      vr0 = *reinterpret_cast<const u16x8*>(vsrc + m0 + 64);
      vr1 = *reinterpret_cast<const u16x8*>(vsrc + m0 + 72);
    }

    // QK^T (base-2 units, log2e folded into Wq): s0 = m-rows 0..31, s1 = 32..63
    f32x16 s0, s1;
#pragma unroll
    for (int r = 0; r < 16; ++r) { s0[r] = 0.f; s1[r] = 0.f; }
    __builtin_amdgcn_s_setprio(1);
#pragma unroll
    for (int kc = 0; kc < 4; ++kc) {
      bf16x8 ka0 = *reinterpret_cast<const bf16x8*>(&Kl[(l31) * LST + kc * 16 + hi * 8]);
      bf16x8 ka1 = *reinterpret_cast<const bf16x8*>(&Kl[(32 + l31) * LST + kc * 16 + hi * 8]);
      s0 = __builtin_amdgcn_mfma_f32_32x32x16_bf16(ka0, qb[kc], s0, 0, 0, 0);
      s1 = __builtin_amdgcn_mfma_f32_32x32x16_bf16(ka1, qb[kc], s1, 0, 0, 0);
    }
    __builtin_amdgcn_s_setprio(0);

    // defer-max: per-lane q column (q = l31); partner half via one xor-32
    float mx = fmaxf(s0[0], s1[0]);
#pragma unroll
    for (int r = 1; r < 16; ++r) mx = fmaxf(mx, fmaxf(s0[r], s1[r]));
    mx = fmaxf(mx, __shfl_xor(mx, 32));
    if (!__all(mx <= mrun + 11.5f)) {
      float mnew = fmaxf(mrun, mx);
      float scl = __builtin_amdgcn_exp2f(mrun - mnew);
      lsum *= scl;
#pragma unroll
      for (int r = 0; r < 16; ++r) {
        float sclr = __shfl(scl, (r & 3) + 8 * (r >> 2) + 4 * hi);
        accO0[r] *= sclr;
        accO1[r] *= sclr;
      }
      mrun = mnew;
    }

    // p = exp2(S - mrun), lane-local sum (no per-tile cross-lane reduce)
    float lst = 0.f;
#pragma unroll
    for (int r = 0; r < 16; ++r) {
      s0[r] = __builtin_amdgcn_exp2f(s0[r] - mrun);
      s1[r] = __builtin_amdgcn_exp2f(s1[r] - mrun);
      lst += s0[r] + s1[r];
    }
    lsum += lst;

    // pack p -> bf16 pairs
    unsigned int W0[8], W1[8];
#pragma unroll
    for (int j = 0; j < 8; ++j) {
      W0[j] = cvtpk(s0[2 * j], s0[2 * j + 1]);
      W1[j] = cvtpk(s1[2 * j], s1[2 * j + 1]);
    }

    // PV: pa[kc4] = A[q=l31][m = kc4*16 + hi*8 + e] built via 2 xor-32 shuffles
    __builtin_amdgcn_s_setprio(1);
#pragma unroll
    for (int kc4 = 0; kc4 < 4; ++kc4) {
      const unsigned int* Wm = (kc4 < 2) ? W0 : W1;
      const int b = 4 * (kc4 & 1);
      unsigned int sv1 = (unsigned int)__shfl_xor((int)(hi ? Wm[b] : Wm[b + 2]), 32);
      unsigned int sv2 = (unsigned int)__shfl_xor((int)(hi ? Wm[b + 1] : Wm[b + 3]), 32);
      union { unsigned int u[4]; bf16x8 v; } c;
      c.u[0] = hi ? sv1 : Wm[b];
      c.u[1] = hi ? sv2 : Wm[b + 1];
      c.u[2] = hi ? Wm[b + 2] : sv1;
      c.u[3] = hi ? Wm[b + 3] : sv2;
      bf16x8 vb0 = *reinterpret_cast<const bf16x8*>(&Vl[(l31) * LST + kc4 * 16 + hi * 8]);
      bf16x8 vb1 = *reinterpret_cast<const bf16x8*>(&Vl[(32 + l31) * LST + kc4 * 16 + hi * 8]);
      accO0 = __builtin_amdgcn_mfma_f32_32x32x16_bf16(c.v, vb0, accO0, 0, 0, 0);
      accO1 = __builtin_amdgcn_mfma_f32_32x32x16_bf16(c.v, vb1, accO1, 0, 0, 0);
    }
    __builtin_amdgcn_s_setprio(0);
    __syncthreads();
  }

  // finalize: full sum per q = own + partner half
  lsum += __shfl_xor(lsum, 32);
  float linv = 1.f / lsum;
#pragma unroll
  for (int r = 0; r < 16; ++r) {
    const int qrow = (r & 3) + 8 * (r >> 2) + 4 * hi;
    float lr = __shfl(linv, qrow);
    const long row = n0 + w * 32 + qrow;
    Op[base + row * 1024 + l31] = f2bf(accO0[r] * lr);
    Op[base + row * 1024 + 32 + l31] = f2bf(accO1[r] * lr);
  }
}

extern "C" void kernel_launch(void* const* d_in, const int* in_sizes, int n_in,
                              void* d_out, int out_size, void* d_ws, size_t ws_size,
                              hipStream_t stream) {
  const float* q    = (const float*)d_in[0];
  const float* k    = (const float*)d_in[1];
  const float* v    = (const float*)d_in[2];
  const float* wq   = (const float*)d_in[3];
  const float* wk   = (const float*)d_in[4];
  const float* wv   = (const float*)d_in[5];
  const float* wp   = (const float*)d_in[6];
  const float* bias = (const float*)d_in[7];

  unsigned short* ws = (unsigned short*)d_ws;
  unsigned short* Wq = ws;
  unsigned short* Wk = Wq + (1 << 20);
  unsigned short* Wv = Wk + (1 << 20);
  unsigned short* Wp = Wv + (1 << 20);
  unsigned short* qp = Wp + (1 << 20);
  unsigned short* kp = qp + (8 << 20);
  unsigned short* vt = kp + (8 << 20);
  unsigned short* mh = vt + (8 << 20);

  // fold 1/sqrt(64) * log2(e) into Wq -> softmax runs in base 2
  pack_wqkv<<<256, 256, 0, stream>>>(wq, Wq, 0.125f * 1.44269504089f);
  pack_wqkv<<<256, 256, 0, stream>>>(wk, Wk, 1.0f);
  pack_wqkv<<<256, 256, 0, stream>>>(wv, Wv, 1.0f);
  pack_wp  <<<256, 256, 0, stream>>>(wp, Wp);

  dim3 gg(8, 128);  // (1024/128 col tiles, 8192/64 row tiles)
  gemm_k<true, false, false><<<gg, 256, 0, stream>>>(q, Wq, qp, nullptr);
  gemm_k<true, false, false><<<gg, 256, 0, stream>>>(k, Wk, kp, nullptr);
  gemm_k<true, false, true ><<<gg, 256, 0, stream>>>(v, Wv, vt, nullptr);  // -> Vt_g[b][col][m]

  attn_k<<<dim3(16, 64), 256, 0, stream>>>(qp, kp, vt, mh);

  gemm_k<false, true, false><<<gg, 256, 0, stream>>>(mh, Wp, d_out, bias);
}